// Round 2
// baseline (741.557 us; speedup 1.0000x reference)
//
#include <hip/hip_runtime.h>
#include <hip/hip_bf16.h>

// TT layer via MFMA bf16:
// out[n,a,b,c,d] = relu( sum x[n,ijkl] G1[a,i,r] G2[b,j,r,s] G3[c,k,s,t] G4[d,l,t] + bias[abcd] )
//
// prep:    one block converts G1..G4 fp32->bf16 into padded LDS-image layouts in d_ws
//          (g1s K-cols 16..31 zeroed -> xs upper halves may be garbage).
// prep_x:  converts+transposes x into per-(n,k) swizzled xs images (bf16, 8KB each):
//          row r=(j*16+l) has 16 i-cols; 16B half h stored at slot h ^ ((r>>2)&1)
//          (bank spread for the stage-1 frag reads). passA stages these LINEARLY
//          via global_load_lds (wave-private rows -> no staging barrier, no VALU).
// Pass A (block = n, k-pair): stage1: T1[(j,l),(a,r)] = x^T G1 (K=16, zeros in G1 pad)
//                             stage2: T2[(a,l),(b,s)] = T1 G2  (K=64)
//                             stage2 result written DIRECTLY to global T2 (u64/lane,
//                             quads form 32B runs) -> no store phase, 2 barriers/k.
// Pass B (block = n, a):      stage3: T3[(b,l),(c,t)] = T2 G3  (K=64)
//                             stage4: out[(b,c),d]    = T3 G4  (K=64) + bias, relu
//
// MFMA 16x16x32 bf16 layouts (gfx950, HW-verified per guide):
//   A frag: lane holds A[m=ln][k=quad*8+j]; B frag: B[k=quad*8+j][n=ln]
//   C/D: col=ln, row=quad*4+reg. Swapped mfma(B,A) = C^T -> regs span the N index,
//   so inter-stage repack is a packed write (u64).

typedef __attribute__((ext_vector_type(8))) short bf16x8;
typedef __attribute__((ext_vector_type(4))) float f32x4;
typedef unsigned short u16;
typedef unsigned long long u64;

#define T2_PER_N 262144           // 16(a) * 256(kl) * 64(b*4+s) bf16 elems
#define PAD40 40                  // 16 real K + 16 zeros + 8 pad (g1 rows)
#define PAD72 72                  // 64 K + 8 pad (144B rows, 16B aligned)

// d_ws layout (u16 offsets):
//   img:  g1s [64][PAD40] @ 0      (2560)
//         g2s [64][PAD72] @ 2560   (4608)
//         g3s [64][PAD72] @ 7168   (4608)
//         g4s [16][PAD72] @ 11776  (1152)  -> 12928 total, reserve 16384 (32 KB)
//   xb:   @ 16384, 1024 samples * 16 k * 4096 u16 (8 KB) = 128 MB
//   T2:   @ 16384 + 67108864

static __device__ __forceinline__ u16 f2bf(float f) {
  __hip_bfloat16 h = __float2bfloat16(f);
  return *reinterpret_cast<u16*>(&h);
}
static __device__ __forceinline__ u64 pack4(f32x4 a) {
  union { u16 s[4]; u64 u; } p;
  p.s[0] = f2bf(a[0]); p.s[1] = f2bf(a[1]); p.s[2] = f2bf(a[2]); p.s[3] = f2bf(a[3]);
  return p.u;
}
static __device__ __forceinline__ void gload_lds16(const void* g, void* l) {
  __builtin_amdgcn_global_load_lds(
      (const __attribute__((address_space(1))) unsigned int*)g,
      (__attribute__((address_space(3))) unsigned int*)l, 16, 0, 0);
}
#define MFMA(A, B, C) __builtin_amdgcn_mfma_f32_16x16x32_bf16((A), (B), (C), 0, 0, 0)

__global__ void tt_prep(const float* __restrict__ G1, const float* __restrict__ G2,
                        const float* __restrict__ G3, const float* __restrict__ G4,
                        u16* __restrict__ img)
{
  const int tid = threadIdx.x;
  const uint4 z = {0, 0, 0, 0};
  for (int idx = tid; idx < 1616; idx += 256) ((uint4*)img)[idx] = z;  // 12928 u16
  __syncthreads();
  #pragma unroll
  for (int it = 0; it < 4; ++it) {   // G1[a,i,r] -> g1s[(a*4+r)][i]  (cols 16..31 stay 0)
    const int e = it * 256 + tid, a = e >> 6, i = (e >> 2) & 15, r = e & 3;
    img[(a * 4 + r) * PAD40 + i] = f2bf(G1[e]);
  }
  #pragma unroll
  for (int it = 0; it < 16; ++it) {  // G2[b,j,r,s] -> g2s[(b*4+s)][j*4+r]
    const int e = it * 256 + tid, b = e >> 8, j = (e >> 4) & 15, r = (e >> 2) & 3, s = e & 3;
    img[2560 + (b * 4 + s) * PAD72 + j * 4 + r] = f2bf(G2[e]);
  }
  #pragma unroll
  for (int it = 0; it < 16; ++it) {  // G3[c,k,s,t] -> g3s[(c*4+t)][k*4+s]
    const int e = it * 256 + tid, c = e >> 8, k = (e >> 4) & 15, s = (e >> 2) & 3, t = e & 3;
    img[7168 + (c * 4 + t) * PAD72 + k * 4 + s] = f2bf(G3[e]);
  }
  #pragma unroll
  for (int it = 0; it < 4; ++it) {   // G4[d,l,t] -> g4s[d][t*16+l]
    const int e = it * 256 + tid, d = e >> 6, l = (e >> 2) & 15, t = e & 3;
    img[11776 + d * PAD72 + t * 16 + l] = f2bf(G4[e]);
  }
}

// x[n,i,j,k,l] fp32 -> xb per-(n,k) image: row r=(j*16+l) * 16 cols (i),
// 16B half h at slot h^((r>>2)&1). Block = (k-quad, n).
__global__ __launch_bounds__(256, 4) void tt_prep_x(const float* __restrict__ x,
                                                    u16* __restrict__ xb)
{
  const int tid = threadIdx.x;
  const int kq = blockIdx.x;                 // k = kq*4 + kk
  const int n  = blockIdx.y;
  __shared__ __align__(16) u16 im[4 * 4112]; // 4 images, 32B inter-image pad (bank spread)
  const int lane = tid & 63, wv = tid >> 6;
  const int j2 = lane >> 4, kk = (lane >> 2) & 3, lq = lane & 3;
  const float4* xg = (const float4*)x + (size_t)n * 16384;
  const int j = wv * 4 + j2, k = kq * 4 + kk;
  #pragma unroll
  for (int i = 0; i < 16; ++i) {
    const float4 v = xg[i * 1024 + j * 64 + k * 4 + lq];
    const int sb = (i >> 3) ^ (lq & 1);      // (r>>2)&1 == lq&1 for r=j*16+lq*4+u
    const int base = kk * 4112 + (j * 16 + lq * 4) * 16 + sb * 8 + (i & 7);
    im[base]      = f2bf(v.x);
    im[base + 16] = f2bf(v.y);
    im[base + 32] = f2bf(v.z);
    im[base + 48] = f2bf(v.w);
  }
  __syncthreads();
  uint4* xo = (uint4*)(xb + (size_t)n * 65536 + (size_t)kq * 16384);
  #pragma unroll
  for (int it = 0; it < 8; ++it) {           // linear, coalesced image dump
    const int e = it * 256 + tid, kk2 = e >> 9, off = e & 511;
    xo[e] = *(const uint4*)&im[kk2 * 4112 + off * 8];
  }
}

__global__ __launch_bounds__(512, 4) void tt_passA(
    const u16* __restrict__ xb, const u16* __restrict__ img,
    u16* __restrict__ T2, int n0)
{
  const int tid = threadIdx.x;
  const int kp   = blockIdx.x;               // k = 2*kp + kx
  const int slot = blockIdx.y;
  const int n = n0 + slot;
  const int lane = tid & 63, w = tid >> 6, quad = (lane >> 4) & 3, ln = lane & 15;

  __shared__ __align__(16) u16 gAs[7168];        // g1s @0 [64][40], g2s @2560 [64][72]
  __shared__ __align__(16) u16 xs [2 * 4096];    // 2 swizzled k-images [256 rows][16]
  __shared__ __align__(16) u16 t1s[256 * PAD72]; // A2: [m2=a*16+l][k2=j*4+r]

  // ---- async staging: G images (shared) + this wave's private xs rows ----
  for (int c = w; c < 14; c += 8)
    gload_lds16(img + c * 512 + lane * 8, &gAs[c * 512]);
  const u16* xbn = xb + (size_t)n * 65536;
  #pragma unroll
  for (int kx = 0; kx < 2; ++kx)
    gload_lds16(xbn + (kp * 2 + kx) * 4096 + w * 512 + lane * 8, &xs[kx * 4096 + w * 512]);
  asm volatile("s_waitcnt vmcnt(0)" ::: "memory");
  __syncthreads();

  u64* Tg = (u64*)(T2 + (size_t)slot * T2_PER_N);
  const int sb = (quad & 1) ^ ((ln >> 2) & 1);   // xs slot swizzle

  #pragma unroll
  for (int kx = 0; kx < 2; ++kx) {
    const int k = kp * 2 + kx;
    if (kx) __syncthreads();  // prev stage2's t1s reads done before rewrite

    // ---- stage 1 (swapped: regs span n1=(a,r); quads 2,3 read dup halves,
    //      zeroed by g1s K-pad) ----
    {
      bf16x8 a1[2];
      #pragma unroll
      for (int t = 0; t < 2; ++t)
        a1[t] = *(const bf16x8*)&xs[kx * 4096 + ((w * 2 + t) * 16 + ln) * 16 + sb * 8];
      #pragma unroll
      for (int tn = 0; tn < 4; ++tn) {
        const bf16x8 b1 = *(const bf16x8*)&gAs[(tn * 16 + ln) * PAD40 + quad * 8];
        #pragma unroll
        for (int t = 0; t < 2; ++t) {
          f32x4 acc = {0.f, 0.f, 0.f, 0.f};
          acc = MFMA(b1, a1[t], acc);     // swapped: row=n1_local, col=m1_local
          // elem (j=w*2+t, l=ln, a=tn*4+quad, r=reg) -> t1s[a*16+l][j*4+r]
          *(u64*)&t1s[((tn * 4 + quad) * 16 + ln) * PAD72 + (w * 2 + t) * 4] = pack4(acc);
        }
      }
    }
    __syncthreads();

    // ---- stage 2 (swapped: regs span n2=(b,s)) -> DIRECT global T2 store ----
    {
      bf16x8 a2[2][2];
      #pragma unroll
      for (int t = 0; t < 2; ++t)
        #pragma unroll
        for (int ks = 0; ks < 2; ++ks)
          a2[t][ks] = *(const bf16x8*)&t1s[((w * 2 + t) * 16 + ln) * PAD72 + ks * 32 + quad * 8];
      const u16* g2s = gAs + 2560;
      #pragma unroll
      for (int tn = 0; tn < 4; ++tn) {
        const bf16x8 b20 = *(const bf16x8*)&g2s[(tn * 16 + ln) * PAD72 + quad * 8];
        const bf16x8 b21 = *(const bf16x8*)&g2s[(tn * 16 + ln) * PAD72 + 32 + quad * 8];
        #pragma unroll
        for (int t = 0; t < 2; ++t) {
          f32x4 acc = {0.f, 0.f, 0.f, 0.f};
          acc = MFMA(b20, a2[t][0], acc);
          acc = MFMA(b21, a2[t][1], acc);
          // elem (a=w*2+t, l=ln, bs=tn*16+quad*4+reg) -> T2[a][k*16+l][bs]
          // quads form contiguous 32B runs per (tn, row).
          const int a = w * 2 + t;
          Tg[(a * 16384 + (k * 16 + ln) * 64 + tn * 16 + quad * 4) >> 2] = pack4(acc);
        }
      }
    }
  }
}

__global__ __launch_bounds__(512, 4) void tt_passB(
    const u16* __restrict__ T2, const u16* __restrict__ img,
    const float* __restrict__ bias, float* __restrict__ out, int n0)
{
  const int tid = threadIdx.x;
  const int a    = blockIdx.x;
  const int slot = blockIdx.y;
  const int n = n0 + slot;
  const int lane = tid & 63, w = tid >> 6, quad = (lane >> 4) & 3, ln = lane & 15;

  __shared__ __align__(16) u16 g3s[4608];         // [64][72]
  __shared__ __align__(16) u16 t2a[256 * PAD72];  // A3: [m3=b*16+l][k3=k*4+s]; reused as A4

  // ---- staging: g3 via async copy; g4 frags straight to regs (L2-hot) ----
  for (int c = w; c < 9; c += 8)
    gload_lds16(img + 7168 + c * 512 + lane * 8, &g3s[c * 512]);
  bf16x8 b4[2];
  #pragma unroll
  for (int ks = 0; ks < 2; ++ks)
    b4[ks] = *(const bf16x8*)&img[11776 + ln * PAD72 + ks * 32 + quad * 8];
  {  // T2[a][k*16+l][bs] (coalesced uint4) -> t2a[b*16+l][k*4+s] (b64 per 4-s group)
    const uint4* Tg = (const uint4*)(T2 + (size_t)slot * T2_PER_N) + a * 2048;
    #pragma unroll
    for (int it = 0; it < 4; ++it) {
      const int e = it * 512 + tid, kl = e >> 3, bq = e & 7;
      const uint4 q = Tg[e];
      const int k = kl >> 4, l = kl & 15, b0 = bq * 2;
      const u64 lo = ((u64)q.y << 32) | q.x, hi = ((u64)q.w << 32) | q.z;
      *(u64*)&t2a[(b0 * 16 + l) * PAD72 + k * 4]       = lo;  // b = b0,   s = 0..3
      *(u64*)&t2a[((b0 + 1) * 16 + l) * PAD72 + k * 4] = hi;  // b = b0+1
    }
  }
  asm volatile("s_waitcnt vmcnt(0)" ::: "memory");
  __syncthreads();

  // ---- stage 3 (normal: regs span m3 -> l, so t3s write packs along k4=t*16+l) ----
  {
    bf16x8 a3[2][2];
    #pragma unroll
    for (int t = 0; t < 2; ++t)
      #pragma unroll
      for (int ks = 0; ks < 2; ++ks)
        a3[t][ks] = *(const bf16x8*)&t2a[((w * 2 + t) * 16 + ln) * PAD72 + ks * 32 + quad * 8];
    __syncthreads();  // all t2a frag reads done before overlay as t3s
    #pragma unroll
    for (int tn = 0; tn < 4; ++tn) {
      const bf16x8 b30 = *(const bf16x8*)&g3s[(tn * 16 + ln) * PAD72 + quad * 8];
      const bf16x8 b31 = *(const bf16x8*)&g3s[(tn * 16 + ln) * PAD72 + 32 + quad * 8];
      #pragma unroll
      for (int t = 0; t < 2; ++t) {
        f32x4 acc = {0.f, 0.f, 0.f, 0.f};
        acc = MFMA(a3[t][0], b30, acc);  // normal: row=m3_local, col=n3_local
        acc = MFMA(a3[t][1], b31, acc);
        // elem (b=w*2+t, l=quad*4+reg, c=tn*4+(ln>>2), t3=ln&3) -> t3s[b*16+c][t3*16+l]
        *(u64*)&t2a[((w * 2 + t) * 16 + tn * 4 + (ln >> 2)) * PAD72 + (ln & 3) * 16 + quad * 4]
            = pack4(acc);
      }
    }
  }
  __syncthreads();

  // ---- stage 4 + epilogue ----
  {
    const size_t obase = (size_t)n * 65536;
    #pragma unroll
    for (int t = 0; t < 2; ++t) {
      bf16x8 a40 = *(const bf16x8*)&t2a[((w * 2 + t) * 16 + ln) * PAD72 + quad * 8];
      bf16x8 a41 = *(const bf16x8*)&t2a[((w * 2 + t) * 16 + ln) * PAD72 + 32 + quad * 8];
      f32x4 acc = {0.f, 0.f, 0.f, 0.f};
      acc = MFMA(a40, b4[0], acc);
      acc = MFMA(a41, b4[1], acc);
      #pragma unroll
      for (int r = 0; r < 4; ++r) {
        const int m4 = (w * 2 + t) * 16 + quad * 4 + r;      // b*16+c
        const int off = a * 4096 + m4 * 16 + ln;             // within-sample offset
        const float v = acc[r] + bias[off];
        out[obase + off] = fmaxf(v, 0.f);
      }
    }
  }
}

extern "C" void kernel_launch(void* const* d_in, const int* in_sizes, int n_in,
                              void* d_out, int out_size, void* d_ws, size_t ws_size,
                              hipStream_t stream) {
  const float* x    = (const float*)d_in[0];
  const float* G1   = (const float*)d_in[1];
  const float* G2   = (const float*)d_in[2];
  const float* G3   = (const float*)d_in[3];
  const float* G4   = (const float*)d_in[4];
  const float* bias = (const float*)d_in[5];
  float* out = (float*)d_out;
  u16* img = (u16*)d_ws;                                   // 32 KB reserved
  u16* xb  = img + 16384;                                  // 128 MB
  u16* T2  = xb + (size_t)1024 * 65536;

  const int Bn = 1024;
  const size_t head = 32768 + (size_t)1024 * 131072;       // img + xb bytes
  const size_t per_n = (size_t)T2_PER_N * sizeof(u16);     // 512 KB
  size_t avail = (ws_size > head) ? (ws_size - head) : 0;
  int chunk = (int)(avail / per_n);
  if (chunk > 256) chunk = 256;         // keep T2 chunk L3-resident
  if (chunk < 1) chunk = 1;

  tt_prep<<<1, 256, 0, stream>>>(G1, G2, G3, G4, img);
  tt_prep_x<<<dim3(4, 1024), 256, 0, stream>>>(x, xb);
  for (int nn0 = 0; nn0 < Bn; nn0 += chunk) {
    const int c = (nn0 + chunk <= Bn) ? chunk : (Bn - nn0);
    tt_passA<<<dim3(8, c), 512, 0, stream>>>(xb, img, T2, nn0);
    tt_passB<<<dim3(16, c), 512, 0, stream>>>(T2, img, bias, out, nn0);
  }
}

// Round 4
// 658.101 us; speedup vs baseline: 1.1268x; 1.1268x over previous
//
#include <hip/hip_runtime.h>
#include <hip/hip_bf16.h>

// TT layer via MFMA bf16:
// out[n,a,b,c,d] = relu( sum x[n,ijkl] G1[a,i,r] G2[b,j,r,s] G3[c,k,s,t] G4[d,l,t] + bias[abcd] )
//
// prep:   one block converts G1..G4 fp32->bf16 into the exact padded LDS image
//         layouts (zero K-pad included) in d_ws; passes stage them as uint4 copies.
// Pass A (block = kp, sample-group of 4): per k-slice
//         stage1: T1[(j,l),(a,r)] = x^T G1 (K=16 zero-padded to 32)
//         stage2: T2[(a,l),(b,s)] = T1 G2  (K=64)
//         -> T2 global [n'][a][k*16+l][b*4+s] bf16 (d_ws)
//         8 k-slice iterations (4 samples x k-pair) with REGISTER PREFETCH of the
//         next iteration's x float4s (T14 issue-early/use-late): HBM gather latency
//         hides under the previous slice's stage1+stage2+store instead of a barrier
//         stall. gAs staging + xs zero-fill amortized 8x.
// Pass B (block = a, sample-group of 8): per sample
//         stage3: T3[(b,l),(c,t)] = T2 G3  (K=64)
//         stage4: out[(b,c),d]    = T3 G4  (K=64) + bias, relu
//         T2 uint4 loads prefetched one sample ahead; g3s staged once; b4 frags and
//         bias values (block-constant a) hoisted to registers.
//
// MFMA 16x16x32 bf16 layouts (gfx950, HW-verified per guide):
//   A frag: lane holds A[m=ln][k=quad*8+j]; B frag: B[k=quad*8+j][n=ln]
//   C/D: col=ln, row=quad*4+reg. Swapped mfma(B,A) = C^T -> regs span the N index,
//   so inter-stage repack is a packed ds_write_b64.

typedef __attribute__((ext_vector_type(8))) short bf16x8;
typedef __attribute__((ext_vector_type(4))) float f32x4;
typedef unsigned short u16;
typedef unsigned long long u64;

#define T2_PER_N 262144           // 16(a) * 256(kl) * 64(b*4+s) bf16 elems
#define PAD40 40                  // 16 real K + 16 zeros + 8 pad (stage-1 rows)
#define PAD72 72                  // 64 K + 8 pad (144B rows, 16B aligned, 2-way)

// G-core image layout in d_ws (u16 offsets):
//   g1s [64][PAD40] @ 0      (2560 u16)
//   g2s [64][PAD72] @ 2560   (4608 u16)   -> gAs = 7168 u16 = 896 uint4
//   g3s [64][PAD72] @ 7168   (4608 u16)
//   g4s [16][PAD72] @ 11776  (1152 u16)
//   T2 region starts at u16 offset 16384 (32 KB).

static __device__ __forceinline__ u16 f2bf(float f) {
  __hip_bfloat16 h = __float2bfloat16(f);
  return *reinterpret_cast<u16*>(&h);
}
static __device__ __forceinline__ u64 pack4(f32x4 a) {
  union { u16 s[4]; u64 u; } p;
  p.s[0] = f2bf(a[0]); p.s[1] = f2bf(a[1]); p.s[2] = f2bf(a[2]); p.s[3] = f2bf(a[3]);
  return p.u;
}
#define MFMA(A, B, C) __builtin_amdgcn_mfma_f32_16x16x32_bf16((A), (B), (C), 0, 0, 0)

__global__ void tt_prep(const float* __restrict__ G1, const float* __restrict__ G2,
                        const float* __restrict__ G3, const float* __restrict__ G4,
                        u16* __restrict__ img)
{
  const int tid = threadIdx.x;
  const uint4 z = {0, 0, 0, 0};
  for (int idx = tid; idx < 1616; idx += 256) ((uint4*)img)[idx] = z;  // 12928 u16
  __syncthreads();
  #pragma unroll
  for (int it = 0; it < 4; ++it) {   // G1[a,i,r] -> g1s[(a*4+r)][i]  (cols 16..31 stay 0)
    const int e = it * 256 + tid, a = e >> 6, i = (e >> 2) & 15, r = e & 3;
    img[(a * 4 + r) * PAD40 + i] = f2bf(G1[e]);
  }
  #pragma unroll
  for (int it = 0; it < 16; ++it) {  // G2[b,j,r,s] -> g2s[(b*4+s)][j*4+r]
    const int e = it * 256 + tid, b = e >> 8, j = (e >> 4) & 15, r = (e >> 2) & 3, s = e & 3;
    img[2560 + (b * 4 + s) * PAD72 + j * 4 + r] = f2bf(G2[e]);
  }
  #pragma unroll
  for (int it = 0; it < 16; ++it) {  // G3[c,k,s,t] -> g3s[(c*4+t)][k*4+s]
    const int e = it * 256 + tid, c = e >> 8, k = (e >> 4) & 15, s = (e >> 2) & 3, t = e & 3;
    img[7168 + (c * 4 + t) * PAD72 + k * 4 + s] = f2bf(G3[e]);
  }
  #pragma unroll
  for (int it = 0; it < 4; ++it) {   // G4[d,l,t] -> g4s[d][t*16+l]
    const int e = it * 256 + tid, d = e >> 6, l = (e >> 2) & 15, t = e & 3;
    img[11776 + d * PAD72 + t * 16 + l] = f2bf(G4[e]);
  }
}

__global__ __launch_bounds__(512, 4) void tt_passA(
    const float* __restrict__ x, const u16* __restrict__ img,
    u16* __restrict__ T2, int n0, int nper)
{
  const int tid = threadIdx.x;
  const int kp  = blockIdx.x;           // k-pair: k = 2*kp + kx
  const int sb  = blockIdx.y * nper;    // first slot of this block's sample group
  const int lane = tid & 63, w = tid >> 6, quad = (lane >> 4) & 3, ln = lane & 15;

  __shared__ __align__(16) u16 gAs[7168];         // g1s @0 [64][40], g2s @2560 [64][72]
  __shared__ __align__(16) u16 xs [256 * PAD40];  // A1: [m1=j*16+l][i 0..15, zeros 16..31]
  __shared__ __align__(16) u16 t1s[256 * PAD72];  // A2: [m2=a*16+l][k2=j*4+r]; reused as T2 staging

  // ---- once per block: G images (pure vector copies) + xs K-pad zero-fill ----
  for (int idx = tid; idx < 896; idx += 512)
    ((uint4*)gAs)[idx] = ((const uint4*)img)[idx];
  {
    const uint4 z = {0, 0, 0, 0};
    const int row = tid >> 1, h = tid & 1;
    *(uint4*)&xs[row * PAD40 + 16 + h * 8] = z;
  }

  // x-staging thread mapping (fixed): thread owns (i, lq, j0) and (i, lq, j0+8)
  const int lq = tid & 3, i = (tid >> 2) & 15, j0 = tid >> 6;
  const size_t xoff0 = (size_t)i * 1024 + j0 * 64 + lq;        // float4 index, + k*4
  const size_t xoff1 = xoff0 + 8 * 64;                         // j0+8
  const int r0 = (j0 * 16 + lq * 4) * PAD40 + i;
  const int r1 = ((j0 + 8) * 16 + lq * 4) * PAD40 + i;

  // prefetch iteration 0
  const float4* xg0 = (const float4*)x + (size_t)(n0 + sb) * 16384;
  float4 p0 = xg0[xoff0 + kp * 8];
  float4 p1 = xg0[xoff1 + kp * 8];

  for (int it = 0; it < 2 * nper; ++it) {
    const int sm = it >> 1, kx = it & 1, k = kp * 2 + kx;
    const float4 c0 = p0, c1 = p1;
    if (it + 1 < 2 * nper) {   // issue next iteration's loads now; they fly under compute
      const int sm2 = (it + 1) >> 1, k2 = kp * 2 + ((it + 1) & 1);
      const float4* xg2 = (const float4*)x + (size_t)(n0 + sb + sm2) * 16384;
      p0 = xg2[xoff0 + k2 * 4];
      p1 = xg2[xoff1 + k2 * 4];
    }
    // ---- x[i,j,k,l] -> xs[j*16+l][i] (r1-verbatim addresses/values) ----
    xs[r0]             = f2bf(c0.x);
    xs[r0 + PAD40]     = f2bf(c0.y);
    xs[r0 + 2 * PAD40] = f2bf(c0.z);
    xs[r0 + 3 * PAD40] = f2bf(c0.w);
    xs[r1]             = f2bf(c1.x);
    xs[r1 + PAD40]     = f2bf(c1.y);
    xs[r1 + 2 * PAD40] = f2bf(c1.z);
    xs[r1 + 3 * PAD40] = f2bf(c1.w);
    __syncthreads();  // xs ready; also fences prev iteration's t1s store-phase reads

    // ---- stage 1 (swapped: regs span n1=(a,r) so t1s write packs along k2=j*4+r) ----
    {
      bf16x8 a1[2];
      #pragma unroll
      for (int t = 0; t < 2; ++t)
        a1[t] = *(const bf16x8*)&xs[((w * 2 + t) * 16 + ln) * PAD40 + quad * 8];
      #pragma unroll
      for (int tn = 0; tn < 4; ++tn) {
        const bf16x8 b1 = *(const bf16x8*)&gAs[(tn * 16 + ln) * PAD40 + quad * 8];
        #pragma unroll
        for (int t = 0; t < 2; ++t) {
          f32x4 acc = {0.f, 0.f, 0.f, 0.f};
          acc = MFMA(b1, a1[t], acc);     // swapped: row=n1_local, col=m1_local
          // elem (j=w*2+t, l=ln, a=tn*4+quad, r=reg) -> t1s[a*16+l][j*4+r]
          *(u64*)&t1s[((tn * 4 + quad) * 16 + ln) * PAD72 + (w * 2 + t) * 4] = pack4(acc);
        }
      }
    }
    __syncthreads();

    // ---- stage 2 (swapped: regs span n2=(b,s) -> T2 staging rows pack along bs) ----
    {
      bf16x8 a2[2][2];
      #pragma unroll
      for (int t = 0; t < 2; ++t)
        #pragma unroll
        for (int ks = 0; ks < 2; ++ks)
          a2[t][ks] = *(const bf16x8*)&t1s[((w * 2 + t) * 16 + ln) * PAD72 + ks * 32 + quad * 8];
      __syncthreads();  // all t1s frag reads done before overlaying it as T2 staging
      const u16* g2s = gAs + 2560;
      #pragma unroll
      for (int tn = 0; tn < 4; ++tn) {
        const bf16x8 b20 = *(const bf16x8*)&g2s[(tn * 16 + ln) * PAD72 + quad * 8];
        const bf16x8 b21 = *(const bf16x8*)&g2s[(tn * 16 + ln) * PAD72 + 32 + quad * 8];
        #pragma unroll
        for (int t = 0; t < 2; ++t) {
          f32x4 acc = {0.f, 0.f, 0.f, 0.f};
          acc = MFMA(b20, a2[t][0], acc);
          acc = MFMA(b21, a2[t][1], acc);
          // elem (a=w*2+t, l=ln, bs=tn*16+quad*4+reg) -> staging row a*16+l
          *(u64*)&t1s[((w * 2 + t) * 16 + ln) * PAD72 + tn * 16 + quad * 4] = pack4(acc);
        }
      }
    }
    __syncthreads();

    // ---- coalesced store: staging row (a*16+l) of 64 bf16 -> T2[a][k*16+l][bs] ----
    {
      uint4* Tg = (uint4*)(T2 + (size_t)(sb + sm) * T2_PER_N);
      #pragma unroll
      for (int s4 = 0; s4 < 4; ++s4) {
        const int e = s4 * 512 + tid, row = e >> 3, seg = e & 7;
        const uint4 q = *(const uint4*)&t1s[row * PAD72 + seg * 8];
        Tg[(row >> 4) * 2048 + k * 128 + (row & 15) * 8 + seg] = q;
      }
    }
    // next iteration's first __syncthreads (after x staging) fences these t1s reads
  }
}

__global__ __launch_bounds__(512, 4) void tt_passB(
    const u16* __restrict__ T2, const u16* __restrict__ img,
    const float* __restrict__ bias, float* __restrict__ out, int n0, int nper)
{
  const int tid = threadIdx.x;
  const int a   = blockIdx.x;
  const int sb  = blockIdx.y * nper;
  const int lane = tid & 63, w = tid >> 6, quad = (lane >> 4) & 3, ln = lane & 15;

  __shared__ __align__(16) u16 g3s[4608];         // [64][72]
  __shared__ __align__(16) u16 t2a[256 * PAD72];  // A3: [m3=b*16+l][k3=k*4+s]; reused as A4

  // ---- once per block: g3s staging; b4 frags + bias hoisted to regs (a is fixed) ----
  for (int idx = tid; idx < 576; idx += 512)
    ((uint4*)g3s)[idx] = ((const uint4*)(img + 7168))[idx];
  bf16x8 b4[2];
  #pragma unroll
  for (int ks = 0; ks < 2; ++ks)   // g4s image rows are 144B (16B-multiple) -> aligned
    b4[ks] = *(const bf16x8*)&img[11776 + ln * PAD72 + ks * 32 + quad * 8];
  float brg[2][4];
  #pragma unroll
  for (int t = 0; t < 2; ++t)
    #pragma unroll
    for (int r = 0; r < 4; ++r)
      brg[t][r] = bias[a * 4096 + ((w * 2 + t) * 16 + quad * 4 + r) * 16 + ln];

  // prefetch slot 0's T2 uint4s
  uint4 p0, p1, p2, p3;
  {
    const uint4* Tg = (const uint4*)(T2 + (size_t)sb * T2_PER_N) + a * 2048;
    p0 = Tg[tid]; p1 = Tg[512 + tid]; p2 = Tg[1024 + tid]; p3 = Tg[1536 + tid];
  }

  for (int itn = 0; itn < nper; ++itn) {
    const int slot = sb + itn;
    const uint4 c0 = p0, c1 = p1, c2 = p2, c3 = p3;
    if (itn + 1 < nper) {   // issue next slot's loads; they fly under this slot's compute
      const uint4* Tg = (const uint4*)(T2 + (size_t)(slot + 1) * T2_PER_N) + a * 2048;
      p0 = Tg[tid]; p1 = Tg[512 + tid]; p2 = Tg[1024 + tid]; p3 = Tg[1536 + tid];
    }
    if (itn) __syncthreads();  // prev stage-4 t2a reads done before re-staging

    // ---- T2[a][k*16+l][bs] -> t2a[b*16+l][k*4+s] (b64 per 4-s group) ----
    {
      const uint4 cc[4] = {c0, c1, c2, c3};
      #pragma unroll
      for (int s4 = 0; s4 < 4; ++s4) {
        const int e = s4 * 512 + tid, kl = e >> 3, bq = e & 7;
        const uint4 q = cc[s4];
        const int k = kl >> 4, l = kl & 15, b0 = bq * 2;
        const u64 lo = ((u64)q.y << 32) | q.x, hi = ((u64)q.w << 32) | q.z;
        *(u64*)&t2a[(b0 * 16 + l) * PAD72 + k * 4]       = lo;  // b = b0,   s = 0..3
        *(u64*)&t2a[((b0 + 1) * 16 + l) * PAD72 + k * 4] = hi;  // b = b0+1
      }
    }
    __syncthreads();

    // ---- stage 3 (normal: regs span m3 -> l, so t3s write packs along k4=t*16+l) ----
    {
      bf16x8 a3[2][2];
      #pragma unroll
      for (int t = 0; t < 2; ++t)
        #pragma unroll
        for (int ks = 0; ks < 2; ++ks)
          a3[t][ks] = *(const bf16x8*)&t2a[((w * 2 + t) * 16 + ln) * PAD72 + ks * 32 + quad * 8];
      __syncthreads();  // all t2a frag reads done before overlay as t3s
      #pragma unroll
      for (int tn = 0; tn < 4; ++tn) {
        const bf16x8 b30 = *(const bf16x8*)&g3s[(tn * 16 + ln) * PAD72 + quad * 8];
        const bf16x8 b31 = *(const bf16x8*)&g3s[(tn * 16 + ln) * PAD72 + 32 + quad * 8];
        #pragma unroll
        for (int t = 0; t < 2; ++t) {
          f32x4 acc = {0.f, 0.f, 0.f, 0.f};
          acc = MFMA(a3[t][0], b30, acc);  // normal: row=m3_local, col=n3_local
          acc = MFMA(a3[t][1], b31, acc);
          // elem (b=w*2+t, l=quad*4+reg, c=tn*4+(ln>>2), t3=ln&3) -> t3s[b*16+c][t3*16+l]
          *(u64*)&t2a[((w * 2 + t) * 16 + tn * 4 + (ln >> 2)) * PAD72 + (ln & 3) * 16 + quad * 4]
              = pack4(acc);
        }
      }
    }
    __syncthreads();

    // ---- stage 4 + epilogue ----
    {
      const size_t obase = (size_t)(n0 + slot) * 65536;
      #pragma unroll
      for (int t = 0; t < 2; ++t) {
        bf16x8 a40 = *(const bf16x8*)&t2a[((w * 2 + t) * 16 + ln) * PAD72 + quad * 8];
        bf16x8 a41 = *(const bf16x8*)&t2a[((w * 2 + t) * 16 + ln) * PAD72 + 32 + quad * 8];
        f32x4 acc = {0.f, 0.f, 0.f, 0.f};
        acc = MFMA(a40, b4[0], acc);
        acc = MFMA(a41, b4[1], acc);
        #pragma unroll
        for (int r = 0; r < 4; ++r) {
          const int m4 = (w * 2 + t) * 16 + quad * 4 + r;      // b*16+c
          const int off = a * 4096 + m4 * 16 + ln;             // within-sample offset
          const float v = acc[r] + brg[t][r];
          out[obase + off] = fmaxf(v, 0.f);
        }
      }
    }
  }
}

extern "C" void kernel_launch(void* const* d_in, const int* in_sizes, int n_in,
                              void* d_out, int out_size, void* d_ws, size_t ws_size,
                              hipStream_t stream) {
  const float* x    = (const float*)d_in[0];
  const float* G1   = (const float*)d_in[1];
  const float* G2   = (const float*)d_in[2];
  const float* G3   = (const float*)d_in[3];
  const float* G4   = (const float*)d_in[4];
  const float* bias = (const float*)d_in[5];
  float* out = (float*)d_out;
  u16* img = (u16*)d_ws;
  u16* T2  = (u16*)d_ws + 16384;        // T2 region at +32 KB

  const int Bn = 1024;
  const size_t per_n = (size_t)T2_PER_N * sizeof(u16);  // 512 KB
  size_t avail = (ws_size > 32768) ? (ws_size - 32768) : 0;
  int chunk = (int)(avail / per_n);
  if (chunk > 256) chunk = 256;         // keep T2 chunk L3-resident
  int nsa = 4, nsb = 8;
  if (chunk >= 8) chunk &= ~7;          // keep sample groups whole
  else { nsa = 1; nsb = 1; if (chunk < 1) chunk = 1; }

  tt_prep<<<1, 256, 0, stream>>>(G1, G2, G3, G4, img);
  for (int nn0 = 0; nn0 < Bn; nn0 += chunk) {
    const int c = (nn0 + chunk <= Bn) ? chunk : (Bn - nn0);
    tt_passA<<<dim3(8, (c + nsa - 1) / nsa), 512, 0, stream>>>(x, img, T2, nn0, nsa);
    tt_passB<<<dim3(16, (c + nsb - 1) / nsb), 512, 0, stream>>>(T2, img, bias, out, nn0, nsb);
  }
}